// Round 4
// baseline (5285.004 us; speedup 1.0000x reference)
//
#include <hip/hip_runtime.h>
#include <math.h>

// Problem shape (fixed by setup_inputs)
constexpr int Bb  = 4;
constexpr int Ss  = 2048;
constexpr int Dd  = 1024;
constexpr int Hh  = 16;
constexpr int D3  = 3 * Dd;

// ---------------------------------------------------------------------------
// bf16 helpers (RNE)
// ---------------------------------------------------------------------------
__device__ __forceinline__ unsigned short f2bf(float f) {
  unsigned u = __float_as_uint(f);
  u += 0x7FFFu + ((u >> 16) & 1u);
  return (unsigned short)(u >> 16);
}
__device__ __forceinline__ float bf2f(unsigned short h) {
  return __uint_as_float(((unsigned)h) << 16);
}

// fp32 -> bf16 hi/lo planes (a ~= hi+lo, rel err ~2^-17)
__global__ __launch_bounds__(256) void cvt_split(
    const float* __restrict__ in,
    unsigned short* __restrict__ hi, unsigned short* __restrict__ lo)
{
  const long i = ((long)blockIdx.x * 256 + threadIdx.x) * 4;
  float4 v = *(const float4*)(in + i);
  ushort4 h, l;
  h.x = f2bf(v.x); l.x = f2bf(v.x - bf2f(h.x));
  h.y = f2bf(v.y); l.y = f2bf(v.y - bf2f(h.y));
  h.z = f2bf(v.z); l.z = f2bf(v.z - bf2f(h.z));
  h.w = f2bf(v.w); l.w = f2bf(v.w - bf2f(h.w));
  *(ushort4*)(hi + i) = h;
  *(ushort4*)(lo + i) = l;
}

// ---------------------------------------------------------------------------
// Split-precision bf16 MFMA GEMM:
//   C[M,N] (+)= epilogue( scale * (A[M,K] @ Bw[N,K]^T) + bias )
// acc = AhBh + AhBl + AlBh. 128x128 tile, BK=32, 4 waves, 16x16x32 MFMA,
// global_load_lds(16B), LDS [kslot][row][8] (linear staging order).
// ---------------------------------------------------------------------------
typedef __attribute__((ext_vector_type(8))) short bf16x8;
typedef __attribute__((ext_vector_type(4))) float f32x4;

__device__ __forceinline__ void gload16(const void* g, void* l) {
  __builtin_amdgcn_global_load_lds(
      (const __attribute__((address_space(1))) unsigned int*)g,
      (__attribute__((address_space(3))) unsigned int*)l, 16, 0, 0);
}

__global__ __launch_bounds__(256, 2) void gemm_mfma(
    const unsigned short* __restrict__ Ah, const unsigned short* __restrict__ Al,
    const unsigned short* __restrict__ Bh, const unsigned short* __restrict__ Bl,
    const float* __restrict__ bias,
    float* __restrict__ C, unsigned short* __restrict__ Ch, unsigned short* __restrict__ Cl,
    int M, int N, int K, int lda, int ldb, int ldc,
    float scale, int gelu, int triang, int beta)
{
  if (triang && blockIdx.x > blockIdx.y) return;   // causal-unused hop tiles

  __shared__ __align__(16) unsigned short sA_h[4][128][8];
  __shared__ __align__(16) unsigned short sA_l[4][128][8];
  __shared__ __align__(16) unsigned short sB_h[4][128][8];
  __shared__ __align__(16) unsigned short sB_l[4][128][8];

  const int t = threadIdx.x, lane = t & 63, wid = t >> 6;
  const int wr = wid >> 1, wc = wid & 1;
  const long m0 = (long)blockIdx.y * 128, n0 = (long)blockIdx.x * 128;

  // per-wave staging role: each wave stages one full plane (8KB/kt)
  const unsigned short* gsrc;
  unsigned short (*ldst)[128][8];
  long ld;
  switch (wid) {
    case 0:  gsrc = Ah + m0 * lda; ld = lda; ldst = sA_h; break;
    case 1:  gsrc = Al + m0 * lda; ld = lda; ldst = sA_l; break;
    case 2:  gsrc = Bh + n0 * ldb; ld = ldb; ldst = sB_h; break;
    default: gsrc = Bl + n0 * ldb; ld = ldb; ldst = sB_l; break;
  }

  f32x4 acc[4][4] = {};
  const int fr = lane & 15, kq = lane >> 4;
  const int nkt = K >> 5;

  for (int kt = 0; kt < nkt; ++kt) {
    __syncthreads();
    const unsigned short* s = gsrc + kt * 32;
#pragma unroll
    for (int c = 0; c < 8; ++c)   // chunk: kslot=c>>1, rowhalf=c&1
      gload16(s + (long)((c & 1) * 64 + lane) * ld + (c >> 1) * 8,
              &ldst[c >> 1][(c & 1) * 64][0]);
    __syncthreads();

    bf16x8 a_h[4], a_l[4], b_h[4], b_l[4];
#pragma unroll
    for (int i = 0; i < 4; ++i) {
      a_h[i] = *(const bf16x8*)&sA_h[kq][wr * 64 + i * 16 + fr][0];
      b_h[i] = *(const bf16x8*)&sB_h[kq][wc * 64 + i * 16 + fr][0];
    }
#pragma unroll
    for (int i = 0; i < 4; ++i)
#pragma unroll
      for (int j = 0; j < 4; ++j)
        acc[i][j] = __builtin_amdgcn_mfma_f32_16x16x32_bf16(a_h[i], b_h[j], acc[i][j], 0, 0, 0);
#pragma unroll
    for (int i = 0; i < 4; ++i)
      b_l[i] = *(const bf16x8*)&sB_l[kq][wc * 64 + i * 16 + fr][0];
#pragma unroll
    for (int i = 0; i < 4; ++i)
#pragma unroll
      for (int j = 0; j < 4; ++j)
        acc[i][j] = __builtin_amdgcn_mfma_f32_16x16x32_bf16(a_h[i], b_l[j], acc[i][j], 0, 0, 0);
#pragma unroll
    for (int i = 0; i < 4; ++i)
      a_l[i] = *(const bf16x8*)&sA_l[kq][wr * 64 + i * 16 + fr][0];
#pragma unroll
    for (int i = 0; i < 4; ++i)
#pragma unroll
      for (int j = 0; j < 4; ++j)
        acc[i][j] = __builtin_amdgcn_mfma_f32_16x16x32_bf16(a_l[i], b_h[j], acc[i][j], 0, 0, 0);
  }

  // epilogue: C/D layout col = lane&15, row = (lane>>4)*4 + reg  [m89]
#pragma unroll
  for (int i = 0; i < 4; ++i) {
    const long gr0 = m0 + wr * 64 + i * 16 + kq * 4;
#pragma unroll
    for (int j = 0; j < 4; ++j) {
      const long gc = n0 + wc * 64 + j * 16 + fr;
      const float bv = bias ? bias[gc] : 0.0f;
#pragma unroll
      for (int r = 0; r < 4; ++r) {
        float v = acc[i][j][r] * scale + bv;
        if (gelu) v = 0.5f * v * (1.0f + erff(v * 0.70710678118654752f));
        const long off = (gr0 + r) * (long)ldc + gc;
        if (C) {
          C[off] = beta ? C[off] + v : v;
        } else {
          const unsigned short h = f2bf(v);
          Ch[off] = h;
          Cl[off] = f2bf(v - bf2f(h));
        }
      }
    }
  }
}

// ---------------------------------------------------------------------------
// Per-batch flash attention, fp32, + hopping bias + causal mask.
// Block = 64 q-rows of one head. 256 thr as 16x16. Writes attn hi/lo planes.
// qkv_b: [S, 3D]; hop_b: [S, S]; attn planes: [S, D] rows of this batch.
// ---------------------------------------------------------------------------
__global__ __launch_bounds__(256) void flash_attn_b(
    const float* __restrict__ qkv, const float* __restrict__ hop,
    unsigned short* __restrict__ attn_h, unsigned short* __restrict__ attn_l)
{
  const int qt = blockIdx.x;
  const int h  = blockIdx.y;

  __shared__ float Qs[64][68];
  __shared__ float Ks[64][68];
  __shared__ float Vt[64][68];   // transposed: Vt[d][k]
  __shared__ float Ps[64][68];

  const int t  = threadIdx.x;
  const int tx = t & 15;
  const int ty = t >> 4;

  const float* qbase = qkv + ((long)qt * 64) * D3 + h * 64;
#pragma unroll
  for (int c = 0; c < 4; ++c) {
    const int idx = c * 256 + t;
    const int r = idx >> 4, d0 = (idx & 15) * 4;
    *(float4*)&Qs[r][d0] = *(const float4*)(qbase + (long)r * D3 + d0);
  }

  float m_i[4], l_i[4];
  float acc[4][4] = {};
#pragma unroll
  for (int i = 0; i < 4; ++i) { m_i[i] = -1e30f; l_i[i] = 0.0f; }

  for (int kt = 0; kt <= qt; ++kt) {
    const float* kbase = qkv + ((long)kt * 64) * D3 + Dd + h * 64;
    const float* vbase = qkv + ((long)kt * 64) * D3 + 2 * Dd + h * 64;
    __syncthreads();
#pragma unroll
    for (int c = 0; c < 4; ++c) {
      const int idx = c * 256 + t;
      const int r = idx >> 4, d0 = (idx & 15) * 4;
      *(float4*)&Ks[r][d0] = *(const float4*)(kbase + (long)r * D3 + d0);
      float4 vv = *(const float4*)(vbase + (long)r * D3 + d0);
      Vt[d0 + 0][r] = vv.x; Vt[d0 + 1][r] = vv.y;
      Vt[d0 + 2][r] = vv.z; Vt[d0 + 3][r] = vv.w;
    }
    __syncthreads();

    float s[4][4] = {};
#pragma unroll
    for (int d0 = 0; d0 < 64; d0 += 4) {
      float4 aq[4], bk[4];
#pragma unroll
      for (int i = 0; i < 4; ++i) aq[i] = *(float4*)&Qs[ty + 16 * i][d0];
#pragma unroll
      for (int j = 0; j < 4; ++j) bk[j] = *(float4*)&Ks[tx + 16 * j][d0];
#pragma unroll
      for (int i = 0; i < 4; ++i)
#pragma unroll
        for (int j = 0; j < 4; ++j)
          s[i][j] += aq[i].x * bk[j].x + aq[i].y * bk[j].y +
                     aq[i].z * bk[j].z + aq[i].w * bk[j].w;
    }

#pragma unroll
    for (int i = 0; i < 4; ++i) {
      const int rl = ty + 16 * i;
      const long qr = (long)qt * 64 + rl;
      const float* hrow = hop + qr * Ss + (long)kt * 64;
#pragma unroll
      for (int j = 0; j < 4; ++j) {
        const int cl = tx + 16 * j;
        s[i][j] = s[i][j] * 0.125f + hrow[cl];
        if (kt == qt && cl > rl) s[i][j] = -1e30f;
      }
      float rm = fmaxf(fmaxf(s[i][0], s[i][1]), fmaxf(s[i][2], s[i][3]));
#pragma unroll
      for (int off = 1; off < 16; off <<= 1) rm = fmaxf(rm, __shfl_xor(rm, off));
      const float mn = fmaxf(m_i[i], rm);
      const float corr = expf(m_i[i] - mn);
      float rs = 0.0f;
#pragma unroll
      for (int j = 0; j < 4; ++j) {
        const float p = expf(s[i][j] - mn);
        Ps[rl][tx + 16 * j] = p;
        rs += p;
      }
#pragma unroll
      for (int off = 1; off < 16; off <<= 1) rs += __shfl_xor(rs, off);
      l_i[i] = l_i[i] * corr + rs;
      m_i[i] = mn;
#pragma unroll
      for (int j = 0; j < 4; ++j) acc[i][j] *= corr;
    }
    __syncthreads();

#pragma unroll
    for (int k0 = 0; k0 < 64; k0 += 4) {
      float4 pv[4], vv[4];
#pragma unroll
      for (int i = 0; i < 4; ++i) pv[i] = *(float4*)&Ps[ty + 16 * i][k0];
#pragma unroll
      for (int j = 0; j < 4; ++j) vv[j] = *(float4*)&Vt[tx + 16 * j][k0];
#pragma unroll
      for (int i = 0; i < 4; ++i)
#pragma unroll
        for (int j = 0; j < 4; ++j)
          acc[i][j] += pv[i].x * vv[j].x + pv[i].y * vv[j].y +
                       pv[i].z * vv[j].z + pv[i].w * vv[j].w;
    }
  }

#pragma unroll
  for (int i = 0; i < 4; ++i) {
    const float inv = 1.0f / l_i[i];
    const long qr = (long)qt * 64 + ty + 16 * i;
    unsigned short* oh = attn_h + qr * Dd + h * 64;
    unsigned short* ol = attn_l + qr * Dd + h * 64;
#pragma unroll
    for (int j = 0; j < 4; ++j) {
      const float v = acc[i][j] * inv;
      const unsigned short hh = f2bf(v);
      oh[tx + 16 * j] = hh;
      ol[tx + 16 * j] = f2bf(v - bf2f(hh));
    }
  }
}

// ---------------------------------------------------------------------------
// Residual + LayerNorm, D=1024, 1 block/row.
// Variant A: fp32 inputs -> bf16 hi/lo plane output (x1 for FFN + residual).
// Variant B: plane input (hi+lo) + fp32 input -> fp32 output (final).
// ---------------------------------------------------------------------------
__device__ __forceinline__ float waveRed(float v) {
#pragma unroll
  for (int off = 32; off > 0; off >>= 1) v += __shfl_xor(v, off);
  return v;
}

__device__ __forceinline__ void ln_core(float (&v)[4], int t, float* red1, float* red2,
                                        const float* g, const float* be, float (&o)[4]) {
  float s = waveRed(v[0] + v[1] + v[2] + v[3]);
  if ((t & 63) == 0) red1[t >> 6] = s;
  __syncthreads();
  const float mu = (red1[0] + red1[1] + red1[2] + red1[3]) * (1.0f / Dd);
  float d0 = v[0] - mu, d1 = v[1] - mu, d2 = v[2] - mu, d3 = v[3] - mu;
  float sq = waveRed(d0 * d0 + d1 * d1 + d2 * d2 + d3 * d3);
  if ((t & 63) == 0) red2[t >> 6] = sq;
  __syncthreads();
  const float var = (red2[0] + red2[1] + red2[2] + red2[3]) * (1.0f / Dd);
  const float rstd = rsqrtf(var + 1e-5f);
  float4 gv = *(const float4*)(g + t * 4);
  float4 bv = *(const float4*)(be + t * 4);
  o[0] = d0 * rstd * gv.x + bv.x;
  o[1] = d1 * rstd * gv.y + bv.y;
  o[2] = d2 * rstd * gv.z + bv.z;
  o[3] = d3 * rstd * gv.w + bv.w;
}

__global__ __launch_bounds__(256) void resid_ln_po(
    const float* __restrict__ a, const float* __restrict__ r,
    const float* __restrict__ g, const float* __restrict__ be,
    unsigned short* __restrict__ oh, unsigned short* __restrict__ ol)
{
  const long row = blockIdx.x;
  const int t = threadIdx.x;
  float4 av = *(const float4*)(a + row * Dd + t * 4);
  float4 rv = *(const float4*)(r + row * Dd + t * 4);
  float v[4] = {av.x + rv.x, av.y + rv.y, av.z + rv.z, av.w + rv.w};
  __shared__ float red1[4], red2[4];
  float o[4];
  ln_core(v, t, red1, red2, g, be, o);
  ushort4 h, l;
  h.x = f2bf(o[0]); l.x = f2bf(o[0] - bf2f(h.x));
  h.y = f2bf(o[1]); l.y = f2bf(o[1] - bf2f(h.y));
  h.z = f2bf(o[2]); l.z = f2bf(o[2] - bf2f(h.z));
  h.w = f2bf(o[3]); l.w = f2bf(o[3] - bf2f(h.w));
  *(ushort4*)(oh + row * Dd + t * 4) = h;
  *(ushort4*)(ol + row * Dd + t * 4) = l;
}

__global__ __launch_bounds__(256) void resid_ln_pi(
    const unsigned short* __restrict__ ah, const unsigned short* __restrict__ al,
    const float* __restrict__ r,
    const float* __restrict__ g, const float* __restrict__ be,
    float* __restrict__ out)
{
  const long row = blockIdx.x;
  const int t = threadIdx.x;
  ushort4 hv = *(const ushort4*)(ah + row * Dd + t * 4);
  ushort4 lv = *(const ushort4*)(al + row * Dd + t * 4);
  float4 rv = *(const float4*)(r + row * Dd + t * 4);
  float v[4] = {bf2f(hv.x) + bf2f(lv.x) + rv.x, bf2f(hv.y) + bf2f(lv.y) + rv.y,
                bf2f(hv.z) + bf2f(lv.z) + rv.z, bf2f(hv.w) + bf2f(lv.w) + rv.w};
  __shared__ float red1[4], red2[4];
  float o[4];
  ln_core(v, t, red1, red2, g, be, o);
  float4 ov = {o[0], o[1], o[2], o[3]};
  *(float4*)(out + row * Dd + t * 4) = ov;
}

// ---------------------------------------------------------------------------
extern "C" void kernel_launch(void* const* d_in, const int* in_sizes, int n_in,
                              void* d_out, int out_size, void* d_ws, size_t ws_size,
                              hipStream_t stream) {
  const float* x     = (const float*)d_in[0];
  const float* imag  = (const float*)d_in[1];
  const float* w_qkv = (const float*)d_in[2];
  const float* b_qkv = (const float*)d_in[3];
  const float* w_o   = (const float*)d_in[4];
  const float* b_o   = (const float*)d_in[5];
  const float* ln1g  = (const float*)d_in[6];
  const float* ln1b  = (const float*)d_in[7];
  const float* w1    = (const float*)d_in[8];
  const float* b1    = (const float*)d_in[9];
  const float* w2    = (const float*)d_in[10];
  const float* b2    = (const float*)d_in[11];
  const float* ln2g  = (const float*)d_in[12];
  const float* ln2b  = (const float*)d_in[13];
  float* out = (float*)d_out;
  char* w = (char*)d_ws;

  // Workspace layout — TOTAL 128 MB. Aliases valid per dataflow order.
  enum : size_t {
    O_WSLOT = 0,           // 16MB: wqkv planes -> wo planes -> w1 planes
    O_XH    = 16777216,    // 16MB x hi            | later: aliased (see below)
    O_XL    = 33554432,    // 16MB x lo
    O_IMGH  = 50331648,    //  4MB imag_b hi
    O_IMGL  = 54525952,    //  4MB imag_b lo
    O_HOPB  = 58720256,    // 16MB hop_b fp32
    O_QKVB  = 75497472,    // 24MB qkv_b fp32
    O_W2PH  = 83886080,    //  8MB w2 hi (after flash; over qkv_b tail)
    O_W2PL  = 92274688,    //  8MB w2 lo
    O_ATTNH = 100663296,   // 16MB attn hi         | later: x1 hi
    O_ATTNL = 117440512,   // 16MB attn lo         | later: x1 lo
    O_AOUT  = 16777216,    // 32MB attn_out fp32 (over x planes, dead)
    O_HBH   = 16777216,    // 16MB hb slice hi (over attn_out, dead)
    O_HBL   = 33554432,    // 16MB hb slice lo
    O_FFN   = 50331648,    // 32MB ffn_out fp32 (over imgb/hopb/qkvb-head, dead)
    O_X1H   = 100663296,   // x1 planes over attn planes (dead)
    O_X1L   = 117440512
  };
  auto U = [&](size_t o) { return (unsigned short*)(w + o); };
  auto F = [&](size_t o) { return (float*)(w + o); };
  dim3 blk(256);

  // x planes + w_qkv planes
  cvt_split<<<8192, blk, 0, stream>>>(x, U(O_XH), U(O_XL));
  cvt_split<<<3072, blk, 0, stream>>>(w_qkv, U(O_WSLOT), U(O_WSLOT + 6291456));

  // per-batch: hop_b, qkv_b, flash -> attn planes
  for (int b = 0; b < Bb; ++b) {
    const long xoff = (long)b * Ss * Dd;
    cvt_split<<<2048, blk, 0, stream>>>(imag + xoff, U(O_IMGH), U(O_IMGL));
    gemm_mfma<<<dim3(16, 16), blk, 0, stream>>>(          // hop_b = imag_b imag_b^T/32
        U(O_IMGH), U(O_IMGL), U(O_IMGH), U(O_IMGL), nullptr,
        F(O_HOPB), nullptr, nullptr, Ss, Ss, Dd, Dd, Dd, Ss, 0.03125f, 0, 1, 0);
    gemm_mfma<<<dim3(24, 16), blk, 0, stream>>>(          // qkv_b = x_b wqkv^T + b
        U(O_XH) + xoff, U(O_XL) + xoff, U(O_WSLOT), U(O_WSLOT + 6291456), b_qkv,
        F(O_QKVB), nullptr, nullptr, Ss, D3, Dd, Dd, Dd, D3, 1.0f, 0, 0, 0);
    flash_attn_b<<<dim3(Ss / 64, Hh), blk, 0, stream>>>(
        F(O_QKVB), F(O_HOPB), U(O_ATTNH) + xoff, U(O_ATTNL) + xoff);
  }

  // attn_out = attn @ w_o^T + b_o
  cvt_split<<<1024, blk, 0, stream>>>(w_o, U(O_WSLOT), U(O_WSLOT + 2097152));
  gemm_mfma<<<dim3(8, 64), blk, 0, stream>>>(
      U(O_ATTNH), U(O_ATTNL), U(O_WSLOT), U(O_WSLOT + 2097152), b_o,
      F(O_AOUT), nullptr, nullptr, Bb * Ss, Dd, Dd, Dd, Dd, Dd, 1.0f, 0, 0, 0);

  // x1 = LN(x + attn_out) -> planes
  resid_ln_po<<<dim3(Bb * Ss), blk, 0, stream>>>(x, F(O_AOUT), ln1g, ln1b,
                                                 U(O_X1H), U(O_X1L));

  // FFN in 4 hidden-slices of 1024: hb_s = gelu(x1 w1_s^T + b1_s);
  // ffn_out (+)= hb_s w2_s^T (+ b2 on s=0)
  cvt_split<<<4096, blk, 0, stream>>>(w1, U(O_WSLOT), U(O_WSLOT + 8388608));
  cvt_split<<<4096, blk, 0, stream>>>(w2, U(O_W2PH), U(O_W2PL));
  for (int s = 0; s < 4; ++s) {
    const long w1off = (long)s * 1024 * Dd;
    gemm_mfma<<<dim3(8, 64), blk, 0, stream>>>(
        U(O_X1H), U(O_X1L), U(O_WSLOT) + w1off, U(O_WSLOT + 8388608) + w1off, b1 + s * 1024,
        nullptr, U(O_HBH), U(O_HBL), Bb * Ss, 1024, Dd, Dd, Dd, 1024, 1.0f, 1, 0, 0);
    gemm_mfma<<<dim3(8, 64), blk, 0, stream>>>(
        U(O_HBH), U(O_HBL), U(O_W2PH) + s * 1024, U(O_W2PL) + s * 1024,
        s == 0 ? b2 : nullptr,
        F(O_FFN), nullptr, nullptr, Bb * Ss, Dd, 1024, 1024, 4096, Dd,
        1.0f, 0, 0, s == 0 ? 0 : 1);
  }

  // out = LN(x1 + ffn_out)
  resid_ln_pi<<<dim3(Bb * Ss), blk, 0, stream>>>(U(O_X1H), U(O_X1L), F(O_FFN),
                                                 ln2g, ln2b, out);
}

// Round 5
// 3121.636 us; speedup vs baseline: 1.6930x; 1.6930x over previous
//
#include <hip/hip_runtime.h>
#include <math.h>

constexpr int Bb = 4;
constexpr int Ss = 2048;
constexpr int Dd = 1024;
constexpr int Hh = 16;
constexpr int D3 = 3 * Dd;

__device__ __forceinline__ unsigned short f2bf(float f) {
  unsigned u = __float_as_uint(f);
  u += 0x7FFFu + ((u >> 16) & 1u);
  return (unsigned short)(u >> 16);
}
__device__ __forceinline__ float bf2f(unsigned short h) {
  return __uint_as_float(((unsigned)h) << 16);
}

__global__ __launch_bounds__(256) void cvt_split(
    const float* __restrict__ in,
    unsigned short* __restrict__ hi, unsigned short* __restrict__ lo)
{
  const long i = ((long)blockIdx.x * 256 + threadIdx.x) * 4;
  float4 v = *(const float4*)(in + i);
  ushort4 h, l;
  h.x = f2bf(v.x); l.x = f2bf(v.x - bf2f(h.x));
  h.y = f2bf(v.y); l.y = f2bf(v.y - bf2f(h.y));
  h.z = f2bf(v.z); l.z = f2bf(v.z - bf2f(h.z));
  h.w = f2bf(v.w); l.w = f2bf(v.w - bf2f(h.w));
  *(ushort4*)(hi + i) = h;
  *(ushort4*)(lo + i) = l;
}

typedef __attribute__((ext_vector_type(8))) short bf16x8;
typedef __attribute__((ext_vector_type(4))) short bf16x4;
typedef __attribute__((ext_vector_type(4))) float f32x4;
#define MFMA16 __builtin_amdgcn_mfma_f32_16x16x32_bf16

__device__ __forceinline__ void gload16(const void* g, void* l) {
  __builtin_amdgcn_global_load_lds(
      (const __attribute__((address_space(1))) unsigned int*)g,
      (__attribute__((address_space(3))) unsigned int*)l, 16, 0, 0);
}

__global__ __launch_bounds__(256, 2) void gemm_mfma(
    const unsigned short* __restrict__ Ah, const unsigned short* __restrict__ Al,
    const unsigned short* __restrict__ Bh, const unsigned short* __restrict__ Bl,
    const float* __restrict__ bias,
    float* __restrict__ C, unsigned short* __restrict__ Ch, unsigned short* __restrict__ Cl,
    unsigned short* __restrict__ Vth, unsigned short* __restrict__ Vtl,
    int M, int N, int K, int lda, int ldb, int ldc,
    float scale, int gelu, int triang, int beta, int vt_mode)
{
  if (triang && blockIdx.x > blockIdx.y) return;

  __shared__ __align__(16) unsigned short sA_h[4][128][8];
  __shared__ __align__(16) unsigned short sA_l[4][128][8];
  __shared__ __align__(16) unsigned short sB_h[4][128][8];
  __shared__ __align__(16) unsigned short sB_l[4][128][8];

  const int t = threadIdx.x, lane = t & 63, wid = t >> 6;
  const int wr = wid >> 1, wc = wid & 1;
  const long m0 = (long)blockIdx.y * 128, n0 = (long)blockIdx.x * 128;

  const unsigned short* gsrc;
  unsigned short (*ldst)[128][8];
  long ld;
  switch (wid) {
    case 0:  gsrc = Ah + m0 * lda; ld = lda; ldst = sA_h; break;
    case 1:  gsrc = Al + m0 * lda; ld = lda; ldst = sA_l; break;
    case 2:  gsrc = Bh + n0 * ldb; ld = ldb; ldst = sB_h; break;
    default: gsrc = Bl + n0 * ldb; ld = ldb; ldst = sB_l; break;
  }

  f32x4 acc[4][4] = {};
  const int fr = lane & 15, kq = lane >> 4;
  const int nkt = K >> 5;

  for (int kt = 0; kt < nkt; ++kt) {
    __syncthreads();
    const unsigned short* s = gsrc + kt * 32;
#pragma unroll
    for (int c = 0; c < 8; ++c)
      gload16(s + (long)((c & 1) * 64 + lane) * ld + (c >> 1) * 8,
              &ldst[c >> 1][(c & 1) * 64][0]);
    __syncthreads();

    bf16x8 a_h[4], a_l[4], b_h[4], b_l[4];
#pragma unroll
    for (int i = 0; i < 4; ++i) {
      a_h[i] = *(const bf16x8*)&sA_h[kq][wr * 64 + i * 16 + fr][0];
      b_h[i] = *(const bf16x8*)&sB_h[kq][wc * 64 + i * 16 + fr][0];
    }
#pragma unroll
    for (int i = 0; i < 4; ++i)
#pragma unroll
      for (int j = 0; j < 4; ++j)
        acc[i][j] = MFMA16(a_h[i], b_h[j], acc[i][j], 0, 0, 0);
#pragma unroll
    for (int i = 0; i < 4; ++i)
      b_l[i] = *(const bf16x8*)&sB_l[kq][wc * 64 + i * 16 + fr][0];
#pragma unroll
    for (int i = 0; i < 4; ++i)
#pragma unroll
      for (int j = 0; j < 4; ++j)
        acc[i][j] = MFMA16(a_h[i], b_l[j], acc[i][j], 0, 0, 0);
#pragma unroll
    for (int i = 0; i < 4; ++i)
      a_l[i] = *(const bf16x8*)&sA_l[kq][wr * 64 + i * 16 + fr][0];
#pragma unroll
    for (int i = 0; i < 4; ++i)
#pragma unroll
      for (int j = 0; j < 4; ++j)
        acc[i][j] = MFMA16(a_l[i], b_h[j], acc[i][j], 0, 0, 0);
  }

#pragma unroll
  for (int i = 0; i < 4; ++i) {
    const long gr0 = m0 + wr * 64 + i * 16 + kq * 4;
#pragma unroll
    for (int j = 0; j < 4; ++j) {
      const long gc = n0 + wc * 64 + j * 16 + fr;
      const float bv = bias ? bias[gc] : 0.0f;
#pragma unroll
      for (int r = 0; r < 4; ++r) {
        float v = acc[i][j][r] * scale + bv;
        if (gelu) v = 0.5f * v * (1.0f + erff(v * 0.70710678118654752f));
        const long gr = gr0 + r;
        if (C) {
          const long off = gr * (long)ldc + gc;
          C[off] = beta ? C[off] + v : v;
        } else {
          const unsigned short hh = f2bf(v);
          const unsigned short ll = f2bf(v - bf2f(hh));
          if (!vt_mode) {
            const long off = gr * (long)ldc + gc;
            Ch[off] = hh; Cl[off] = ll;
          } else if (gc < 2048) {
            const long off = gr * 2048 + gc;
            Ch[off] = hh; Cl[off] = ll;
          } else {
            const long off = (gc - 2048) * 2048 + gr;
            Vth[off] = hh; Vtl[off] = ll;
          }
        }
      }
    }
  }
}

__global__ __launch_bounds__(256, 2) void flash_mfma(
    const unsigned short* __restrict__ qkh, const unsigned short* __restrict__ qkl,
    const unsigned short* __restrict__ vth, const unsigned short* __restrict__ vtl,
    const float* __restrict__ hop,
    unsigned short* __restrict__ attn_h, unsigned short* __restrict__ attn_l)
{
  const int qt = blockIdx.x, h = blockIdx.y;
  const int t = threadIdx.x, lane = t & 63, w = t >> 6;
  const int fr = lane & 15, kq = lane >> 4;

  __shared__ __align__(16) unsigned short Kh[64][64];
  __shared__ __align__(16) unsigned short Kl[64][64];
  __shared__ __align__(16) unsigned short Vh[64][64];
  __shared__ __align__(16) unsigned short Vl[64][64];
  __shared__ __align__(16) float Hs[64][64];
  __shared__ __align__(16) unsigned short Ph[4][16][64];
  __shared__ __align__(16) unsigned short Pl[4][16][64];

  bf16x8 qh[2], ql[2];
  {
    const long qrow = (long)qt * 64 + w * 16 + fr;
    const unsigned short* p1 = qkh + qrow * 2048 + h * 64 + kq * 8;
    const unsigned short* p2 = qkl + qrow * 2048 + h * 64 + kq * 8;
    qh[0] = *(const bf16x8*)p1;  qh[1] = *(const bf16x8*)(p1 + 32);
    ql[0] = *(const bf16x8*)p2;  ql[1] = *(const bf16x8*)(p2 + 32);
  }

  float m_run = -1e30f, l_run = 0.0f;
  f32x4 O[4] = {};

  const int lr8 = lane >> 3, lc8 = lane & 7;
  const int hr4 = lane >> 4, hc16 = lane & 15;

  for (int kt = 0; kt <= qt; ++kt) {
    __syncthreads();
    if (w == 0) {
#pragma unroll
      for (int c = 0; c < 8; ++c) {
        const int row = c * 8 + lr8, sl = lc8 ^ (row & 7);
        gload16(qkh + ((long)(kt * 64 + row)) * 2048 + 1024 + h * 64 + sl * 8,
                &Kh[c * 8][0]);
      }
#pragma unroll
      for (int c = 0; c < 4; ++c) {
        const int row = c * 4 + hr4, sl = hc16 ^ (row & 15);
        gload16(hop + ((long)(qt * 64 + row)) * 2048 + kt * 64 + sl * 4,
                &Hs[c * 4][0]);
      }
    } else if (w == 1) {
#pragma unroll
      for (int c = 0; c < 8; ++c) {
        const int row = c * 8 + lr8, sl = lc8 ^ (row & 7);
        gload16(qkl + ((long)(kt * 64 + row)) * 2048 + 1024 + h * 64 + sl * 8,
                &Kl[c * 8][0]);
      }
#pragma unroll
      for (int c = 0; c < 4; ++c) {
        const int row = (c + 4) * 4 + hr4, sl = hc16 ^ (row & 15);
        gload16(hop + ((long)(qt * 64 + row)) * 2048 + kt * 64 + sl * 4,
                &Hs[(c + 4) * 4][0]);
      }
    } else if (w == 2) {
#pragma unroll
      for (int c = 0; c < 8; ++c) {
        const int row = c * 8 + lr8, sl = lc8 ^ (row & 7);
        gload16(vth + ((long)(h * 64 + row)) * 2048 + kt * 64 + sl * 8,
                &Vh[c * 8][0]);
      }
#pragma unroll
      for (int c = 0; c < 4; ++c) {
        const int row = (c + 8) * 4 + hr4, sl = hc16 ^ (row & 15);
        gload16(hop + ((long)(qt * 64 + row)) * 2048 + kt * 64 + sl * 4,
                &Hs[(c + 8) * 4][0]);
      }
    } else {
#pragma unroll
      for (int c = 0; c < 8; ++c) {
        const int row = c * 8 + lr8, sl = lc8 ^ (row & 7);
        gload16(vtl + ((long)(h * 64 + row)) * 2048 + kt * 64 + sl * 8,
                &Vl[c * 8][0]);
      }
#pragma unroll
      for (int c = 0; c < 4; ++c) {
        const int row = (c + 12) * 4 + hr4, sl = hc16 ^ (row & 15);
        gload16(hop + ((long)(qt * 64 + row)) * 2048 + kt * 64 + sl * 4,
                &Hs[(c + 12) * 4][0]);
      }
    }
    __syncthreads();

    f32x4 sacc[4];
#pragma unroll
    for (int tt = 0; tt < 4; ++tt) {
      const int kr = tt * 16 + fr, x7 = fr & 7;
      bf16x8 k0h = *(const bf16x8*)&Kh[kr][((kq) ^ x7) * 8];
      bf16x8 k1h = *(const bf16x8*)&Kh[kr][((4 + kq) ^ x7) * 8];
      bf16x8 k0l = *(const bf16x8*)&Kl[kr][((kq) ^ x7) * 8];
      bf16x8 k1l = *(const bf16x8*)&Kl[kr][((4 + kq) ^ x7) * 8];
      f32x4 a = {};
      a = MFMA16(k0h, qh[0], a, 0, 0, 0);
      a = MFMA16(k1h, qh[1], a, 0, 0, 0);
      a = MFMA16(k0h, ql[0], a, 0, 0, 0);
      a = MFMA16(k1h, ql[1], a, 0, 0, 0);
      a = MFMA16(k0l, qh[0], a, 0, 0, 0);
      a = MFMA16(k1l, qh[1], a, 0, 0, 0);
      sacc[tt] = a;
    }

    float p[4][4];
    float mx = -1e30f;
#pragma unroll
    for (int tt = 0; tt < 4; ++tt) {
      f32x4 hv = *(const f32x4*)&Hs[w * 16 + fr][((tt * 4 + kq) ^ fr) * 4];
#pragma unroll
      for (int r = 0; r < 4; ++r) {
        float sv = sacc[tt][r] * 0.125f + hv[r];
        if (kt == qt && (tt * 16 + kq * 4 + r) > (w * 16 + fr)) sv = -1e30f;
        p[tt][r] = sv;
        mx = fmaxf(mx, sv);
      }
    }
    mx = fmaxf(mx, __shfl_xor(mx, 16));
    mx = fmaxf(mx, __shfl_xor(mx, 32));
    const float m_new = fmaxf(m_run, mx);
    const float corr = __expf(m_run - m_new);
    m_run = m_new;
    float ls = 0.0f;
#pragma unroll
    for (int tt = 0; tt < 4; ++tt) {
      ushort4 hp, lp;
      float v0 = __expf(p[tt][0] - m_new), v1 = __expf(p[tt][1] - m_new);
      float v2 = __expf(p[tt][2] - m_new), v3 = __expf(p[tt][3] - m_new);
      ls += v0 + v1 + v2 + v3;
      hp.x = f2bf(v0); lp.x = f2bf(v0 - bf2f(hp.x));
      hp.y = f2bf(v1); lp.y = f2bf(v1 - bf2f(hp.y));
      hp.z = f2bf(v2); lp.z = f2bf(v2 - bf2f(hp.z));
      hp.w = f2bf(v3); lp.w = f2bf(v3 - bf2f(hp.w));
      const int ws_ = ((tt * 4 + kq) ^ fr) * 4;
      *(ushort4*)&Ph[w][fr][ws_] = hp;
      *(ushort4*)&Pl[w][fr][ws_] = lp;
    }
    ls += __shfl_xor(ls, 16);
    ls += __shfl_xor(ls, 32);
    l_run = l_run * corr + ls;

    const float c0 = __shfl(corr, kq * 4 + 0);
    const float c1 = __shfl(corr, kq * 4 + 1);
    const float c2 = __shfl(corr, kq * 4 + 2);
    const float c3 = __shfl(corr, kq * 4 + 3);
#pragma unroll
    for (int tt = 0; tt < 4; ++tt) {
      O[tt][0] *= c0; O[tt][1] *= c1; O[tt][2] *= c2; O[tt][3] *= c3;
    }

    union PU { struct { bf16x4 lo, hi; } s; bf16x8 v; };
#pragma unroll
    for (int s = 0; s < 2; ++s) {
      PU phf, plf;
      const int w0 = ((s * 8 + kq * 2) ^ fr) * 4;
      const int w1 = ((s * 8 + kq * 2 + 1) ^ fr) * 4;
      phf.s.lo = *(const bf16x4*)&Ph[w][fr][w0];
      phf.s.hi = *(const bf16x4*)&Ph[w][fr][w1];
      plf.s.lo = *(const bf16x4*)&Pl[w][fr][w0];
      plf.s.hi = *(const bf16x4*)&Pl[w][fr][w1];
#pragma unroll
      for (int tt = 0; tt < 4; ++tt) {
        const int dr = tt * 16 + fr, x7 = fr & 7;
        bf16x8 vhf = *(const bf16x8*)&Vh[dr][((s * 4 + kq) ^ x7) * 8];
        bf16x8 vlf = *(const bf16x8*)&Vl[dr][((s * 4 + kq) ^ x7) * 8];
        O[tt] = MFMA16(phf.v, vhf, O[tt], 0, 0, 0);
        O[tt] = MFMA16(phf.v, vlf, O[tt], 0, 0, 0);
        O[tt] = MFMA16(plf.v, vhf, O[tt], 0, 0, 0);
      }
    }
  }

  const float linv = 1.0f / l_run;
  const float iv0 = __shfl(linv, kq * 4 + 0);
  const float iv1 = __shfl(linv, kq * 4 + 1);
  const float iv2 = __shfl(linv, kq * 4 + 2);
  const float iv3 = __shfl(linv, kq * 4 + 3);
  const float iv[4] = {iv0, iv1, iv2, iv3};
#pragma unroll
  for (int tt = 0; tt < 4; ++tt) {
#pragma unroll
    for (int r = 0; r < 4; ++r) {
      const long row = (long)qt * 64 + w * 16 + kq * 4 + r;
      const long col = h * 64 + tt * 16 + fr;
      const float v = O[tt][r] * iv[r];
      const unsigned short hh = f2bf(v);
      attn_h[row * 1024 + col] = hh;
      attn_l[row * 1024 + col] = f2bf(v - bf2f(hh));
    }
  }
}

__device__ __forceinline__ float waveRed(float v) {
#pragma unroll
  for (int off = 32; off > 0; off >>= 1) v += __shfl_xor(v, off);
  return v;
}

__device__ __forceinline__ void ln_core(float (&v)[4], int t, float* red1, float* red2,
                                        const float* g, const float* be, float (&o)[4]) {
  float s = waveRed(v[0] + v[1] + v[2] + v[3]);
  if ((t & 63) == 0) red1[t >> 6] = s;
  __syncthreads();
  const float mu = (red1[0] + red1[1] + red1[2] + red1[3]) * (1.0f / Dd);
  float d0 = v[0] - mu, d1 = v[1] - mu, d2 = v[2] - mu, d3 = v[3] - mu;
  float sq = waveRed(d0 * d0 + d1 * d1 + d2 * d2 + d3 * d3);
  if ((t & 63) == 0) red2[t >> 6] = sq;
  __syncthreads();
  const float var = (red2[0] + red2[1] + red2[2] + red2[3]) * (1.0f / Dd);
  const float rstd = rsqrtf(var + 1e-5f);
  float4 gv = *(const float4*)(g + t * 4);
  float4 bv = *(const float4*)(be + t * 4);
  o[0] = d0 * rstd * gv.x + bv.x;
  o[1] = d1 * rstd * gv.y + bv.y;
  o[2] = d2 * rstd * gv.z + bv.z;
  o[3] = d3 * rstd * gv.w + bv.w;
}

__global__ __launch_bounds__(256) void resid_ln_po(
    const float* __restrict__ a, const float* __restrict__ r,
    const float* __restrict__ g, const float* __restrict__ be,
    unsigned short* __restrict__ oh, unsigned short* __restrict__ ol)
{
  const long row = blockIdx.x;
  const int t = threadIdx.x;
  float4 av = *(const float4*)(a + row * Dd + t * 4);
  float4 rv = *(const float4*)(r + row * Dd + t * 4);
  float v[4] = {av.x + rv.x, av.y + rv.y, av.z + rv.z, av.w + rv.w};
  __shared__ float red1[4], red2[4];
  float o[4];
  ln_core(v, t, red1, red2, g, be, o);
  ushort4 h, l;
  h.x = f2bf(o[0]); l.x = f2bf(o[0] - bf2f(h.x));
  h.y = f2bf(o[1]); l.y = f2bf(o[1] - bf2f(h.y));
  h.z = f2bf(o[2]); l.z = f2bf(o[2] - bf2f(h.z));
  h.w = f2bf(o[3]); l.w = f2bf(o[3] - bf2f(h.w));
  *(ushort4*)(oh + row * Dd + t * 4) = h;
  *(ushort4*)(ol + row * Dd + t * 4) = l;
}

__global__ __launch_bounds__(256) void resid_ln_pi(
    const unsigned short* __restrict__ ah, const unsigned short* __restrict__ al,
    const float* __restrict__ r,
    const float* __restrict__ g, const float* __restrict__ be,
    float* __restrict__ out)
{
  const long row = blockIdx.x;
  const int t = threadIdx.x;
  ushort4 hv = *(const ushort4*)(ah + row * Dd + t * 4);
  ushort4 lv = *(const ushort4*)(al + row * Dd + t * 4);
  float4 rv = *(const float4*)(r + row * Dd + t * 4);
  float v[4] = {bf2f(hv.x) + bf2f(lv.x) + rv.x, bf2f(hv.y) + bf2f(lv.y) + rv.y,
                bf2f(hv.z) + bf2f(lv.z) + rv.z, bf2f(hv.w) + bf2f(lv.w) + rv.w};
  __shared__ float red1[4], red2[4];
  float o[4];
  ln_core(v, t, red1, red2, g, be, o);
  float4 ov = {o[0], o[1], o[2], o[3]};
  *(float4*)(out + row * Dd + t * 4) = ov;
}

extern "C" void kernel_launch(void* const* d_in, const int* in_sizes, int n_in,
                              void* d_out, int out_size, void* d_ws, size_t ws_size,
                              hipStream_t stream) {
  const float* x     = (const float*)d_in[0];
  const float* imag  = (const float*)d_in[1];
  const float* w_qkv = (const float*)d_in[2];
  const float* b_qkv = (const float*)d_in[3];
  const float* w_o   = (const float*)d_in[4];
  const float* b_o   = (const float*)d_in[5];
  const float* ln1g  = (const float*)d_in[6];
  const float* ln1b  = (const float*)d_in[7];
  const float* w1    = (const float*)d_in[8];
  const float* b1    = (const float*)d_in[9];
  const float* w2    = (const float*)d_in[10];
  const float* b2    = (const float*)d_in[11];
  const float* ln2g  = (const float*)d_in[12];
  const float* ln2b  = (const float*)d_in[13];
  float* out = (float*)d_out;
  char* w = (char*)d_ws;

  enum : size_t {
    O_WSLOT = 0,
    O_XH    = 16777216,
    O_XL    = 33554432,
    O_IMGBH = 50331648,
    O_IMGBL = 54525952,
    O_QKH   = 50331648,
    O_QKL   = 58720256,
    O_VTH   = 67108864,
    O_VTL   = 71303168,
    O_HOPB  = 75497472,
    O_ATTNH = 92274688,
    O_ATTNL = 109051904,
    O_AOUT  = 16777216,
    O_HBH   = 16777216,
    O_HBL   = 25165824,
    O_FFN   = 33554432,
    O_W2PH  = 67108864,
    O_W2PL  = 75497472,
    O_X1H   = 92274688,
    O_X1L   = 109051904
  };
  auto U = [&](size_t o) { return (unsigned short*)(w + o); };
  auto F = [&](size_t o) { return (float*)(w + o); };
  dim3 blk(256);

  cvt_split<<<8192, blk, 0, stream>>>(x, U(O_XH), U(O_XL));
  cvt_split<<<3072, blk, 0, stream>>>(w_qkv, U(O_WSLOT), U(O_WSLOT + 6291456));

  for (int b = 0; b < Bb; ++b) {
    const long xoff = (long)b * Ss * Dd;
    cvt_split<<<2048, blk, 0, stream>>>(imag + xoff, U(O_IMGBH), U(O_IMGBL));
    gemm_mfma<<<dim3(16, 16), blk, 0, stream>>>(
        U(O_IMGBH), U(O_IMGBL), U(O_IMGBH), U(O_IMGBL), nullptr,
        F(O_HOPB), nullptr, nullptr, nullptr, nullptr,
        Ss, Ss, Dd, Dd, Dd, Ss, 0.03125f, 0, 1, 0, 0);
    gemm_mfma<<<dim3(24, 16), blk, 0, stream>>>(
        U(O_XH) + xoff, U(O_XL) + xoff, U(O_WSLOT), U(O_WSLOT + 6291456), b_qkv,
        nullptr, U(O_QKH), U(O_QKL), U(O_VTH), U(O_VTL),
        Ss, D3, Dd, Dd, Dd, 0, 1.0f, 0, 0, 0, 1);
    flash_mfma<<<dim3(Ss / 64, Hh), blk, 0, stream>>>(
        U(O_QKH), U(O_QKL), U(O_VTH), U(O_VTL), F(O_HOPB),
        U(O_ATTNH) + xoff, U(O_ATTNL) + xoff);
  }

  cvt_split<<<1024, blk, 0, stream>>>(w_o, U(O_WSLOT), U(O_WSLOT + 2097152));
  gemm_mfma<<<dim3(8, 64), blk, 0, stream>>>(
      U(O_ATTNH), U(O_ATTNL), U(O_WSLOT), U(O_WSLOT + 2097152), b_o,
      F(O_AOUT), nullptr, nullptr, nullptr, nullptr,
      Bb * Ss, Dd, Dd, Dd, Dd, Dd, 1.0f, 0, 0, 0, 0);

  resid_ln_po<<<dim3(Bb * Ss), blk, 0, stream>>>(x, F(O_AOUT), ln1g, ln1b,
                                                 U(O_X1H), U(O_X1L));

  cvt_split<<<4096, blk, 0, stream>>>(w1, U(O_WSLOT), U(O_WSLOT + 8388608));
  cvt_split<<<4096, blk, 0, stream>>>(w2, U(O_W2PH), U(O_W2PL));
  for (int s = 0; s < 8; ++s) {
    const long w1off = (long)s * 512 * Dd;
    gemm_mfma<<<dim3(4, 64), blk, 0, stream>>>(
        U(O_X1H), U(O_X1L), U(O_WSLOT) + w1off, U(O_WSLOT + 8388608) + w1off,
        b1 + s * 512,
        nullptr, U(O_HBH), U(O_HBL), nullptr, nullptr,
        Bb * Ss, 512, Dd, Dd, Dd, 512, 1.0f, 1, 0, 0, 0);
    gemm_mfma<<<dim3(8, 64), blk, 0, stream>>>(
        U(O_HBH), U(O_HBL), U(O_W2PH) + s * 512, U(O_W2PL) + s * 512,
        s == 0 ? b2 : nullptr,
        F(O_FFN), nullptr, nullptr, nullptr, nullptr,
        Bb * Ss, Dd, 512, 512, 4096, Dd, 1.0f, 0, 0, s == 0 ? 0 : 1, 0);
  }

  resid_ln_pi<<<dim3(Bb * Ss), blk, 0, stream>>>(U(O_X1H), U(O_X1L), F(O_FFN),
                                                 ln2g, ln2b, out);
}